// Round 9
// baseline (245.521 us; speedup 1.0000x reference)
//
#include <hip/hip_runtime.h>
#include <cmath>

// ---------------------------------------------------------------------------
// SwinV2-style window attention, f16-MFMA implementation.  Round 9.
//
// R8->R9:
//  * attn: wave now owns 16 q-rows (was 32); grid (16 qt x 128 bh) = 2048
//    blocks = 8 blocks/CU; __launch_bounds__(256,6).  Doubles resident
//    waves to hide the QK->exp->LDS->PV serial chain.
//  * qkv: separate q/k/v epilogue LDS buffers -> ONE barrier (was 5).
//  * prep_w + bias_mlp fused into one launch.
// ---------------------------------------------------------------------------

typedef _Float16 half_t;
typedef __attribute__((ext_vector_type(4))) _Float16 half4;
typedef __attribute__((ext_vector_type(8))) _Float16 half8;
typedef __attribute__((ext_vector_type(4))) float float4v;

static __device__ __forceinline__ float4v mfma16(half8 a, half8 b, float4v c) {
  return __builtin_amdgcn_mfma_f32_16x16x32_f16(a, b, c, 0, 0, 0);
}

struct PtrArr8 { const float* p[8]; };

// ---------------------------------------------------------------------------
// prep_fused: blocks 0..127 = prep_w (fp32 W -> f16 (+I), fragment layout);
// blocks 128..143 = bias_mlp table.
// W fragment layout: wf[y*16384 + ((ng*4+ks)*64 + quad*16 + l)*8 + (k&7)]
//   = W[j=ng*16+l][k=ks*32+quad*8+(k&7)] (+I for y<6).
// bias table: tabh2[h][p] = 16*sigmoid(mlp(...))*log2e + c14(h).
// ---------------------------------------------------------------------------
__global__ __launch_bounds__(256) void prep_fused(
    PtrArr8 wsrc, PtrArr8 bsrc, const float* __restrict__ w1,
    const float* __restrict__ b1, const float* __restrict__ w2,
    const float* __restrict__ ls, half_t* __restrict__ wf,
    float* __restrict__ bws, float* __restrict__ tabh2) {
  int t = threadIdx.x;
  if (blockIdx.x < 128) {
    int y = blockIdx.x & 7, xb = blockIdx.x >> 3;
    const float* src = nullptr;
    const float* bs = nullptr;
#pragma unroll
    for (int i = 0; i < 8; i++)
      if (i == y) { src = wsrc.p[i]; bs = bsrc.p[i]; }
    int flat = (xb * 256 + t) * 4;
    float4 w = *(const float4*)(src + flat);
    int j = flat >> 7, k = flat & 127;
    if (y < 6) {
      if (k == j)     w.x += 1.0f;
      if (k + 1 == j) w.y += 1.0f;
      if (k + 2 == j) w.z += 1.0f;
      if (k + 3 == j) w.w += 1.0f;
    }
    half4 h;
    h[0] = (half_t)w.x;
    h[1] = (half_t)w.y;
    h[2] = (half_t)w.z;
    h[3] = (half_t)w.w;
    int ng = j >> 4, l = j & 15, ks = k >> 5, quad = (k >> 3) & 3, o8 = k & 7;
    *(half4*)(wf + y * 16384 + ((ng * 4 + ks) * 64 + quad * 16 + l) * 8 +
              o8) = h;
    if (xb == 0 && t < 128) bws[y * 128 + t] = bs[t];
    return;
  }
  // ---- bias MLP part ----
  __shared__ float sw1[256];
  __shared__ float sb1[128];
  __shared__ float sw2[1024];
  sw1[t] = w1[t];
  if (t < 128) sb1[t] = b1[t];
  for (int i = t; i < 1024; i += 256) sw2[i] = w2[i];
  __syncthreads();
  int p = (blockIdx.x - 128) * 256 + t;
  if (p >= 3969) return;
  int ph = p / 63, pw = p % 63;
  float t0 = (float)(ph - 31) * (3.2f / 31.0f);
  float t1 = (float)(pw - 31) * (3.2f / 31.0f);
  t0 = copysignf(1.0f - __expf(-fabsf(t0)), t0);
  t1 = copysignf(1.0f - __expf(-fabsf(t1)), t1);
  float acc[8];
#pragma unroll
  for (int hh = 0; hh < 8; hh++) acc[hh] = 0.0f;
  for (int j = 0; j < 128; j++) {
    float hj = fmaxf(0.0f, t0 * sw1[2 * j] + t1 * sw1[2 * j + 1] + sb1[j]);
#pragma unroll
    for (int hh = 0; hh < 8; hh++) acc[hh] += hj * sw2[hh * 128 + j];
  }
  const float L2E = 1.44269504f;
#pragma unroll
  for (int hh = 0; hh < 8; hh++) {
    float scale = __expf(fminf(ls[hh], 4.6051702f));
    float c14 = 14.0f - (scale + 16.0f) * L2E;
    float bias = 16.0f / (1.0f + __expf(-acc[hh]));
    tabh2[hh * 3969 + p] = bias * L2E + c14;
  }
}

// ---------------------------------------------------------------------------
// qkv_mfma: 3 fused linears (residual folded into W), per-head q/k norm,
// q scaled by scale*log2e.  grid (512 rowtiles-of-32, 2 hf) x 256.
// W-frags direct from global fragment layout.  ONE barrier epilogue.
// ---------------------------------------------------------------------------
__global__ __launch_bounds__(256, 4) void qkv_mfma(
    const float* __restrict__ x, const half_t* __restrict__ wfrag,
    const float* __restrict__ lscale, const float* __restrict__ bws,
    half_t* __restrict__ qf, half_t* __restrict__ kf,
    half_t* __restrict__ vf) {
  __shared__ half_t qbuf[32 * 136];
  __shared__ half_t kbuf[32 * 136];
  __shared__ half_t vbuf[128 * 36];
  int t = threadIdx.x;
  int lane = t & 63, wv = t >> 6, l = lane & 15, quad = lane >> 4;
  int rw = wv & 1, cw = wv >> 1;
  int hf = blockIdx.y;
  int m0 = blockIdx.x * 32;
  int b = m0 >> 10, n0 = m0 & 1023;

  // A fragments: 16 rows (rw strip), this half's 128 channels.
  half8 afr[4];
  {
    const float* xb =
        x + ((size_t)b * 256 + hf * 128) * 1024 + n0 + rw * 16 + l;
#pragma unroll
    for (int ks = 0; ks < 4; ks++) {
      half8 a;
#pragma unroll
      for (int j = 0; j < 8; j++)
        a[j] = (half_t)xb[(size_t)(ks * 32 + quad * 8 + j) * 1024];
      afr[ks] = a;
    }
  }

#pragma unroll
  for (int op = 0; op < 3; op++) {
    int combo = op * 2 + hf;
    const half_t* wfb = wfrag + combo * 16384;
    float4v acc[4];
#pragma unroll
    for (int ngl = 0; ngl < 4; ngl++) {
      int ng = cw * 4 + ngl;
      float4v c = {0.f, 0.f, 0.f, 0.f};
#pragma unroll
      for (int ks = 0; ks < 4; ks++) {
        half8 bfrag = *(const half8*)(wfb + ((ng * 4 + ks) * 64 + lane) * 8);
        c = mfma16(afr[ks], bfrag, c);
      }
      acc[ngl] = c;
    }
#pragma unroll
    for (int ngl = 0; ngl < 4; ngl++) {
      float bb = bws[combo * 128 + (cw * 4 + ngl) * 16 + l];
#pragma unroll
      for (int r2 = 0; r2 < 4; r2++) acc[ngl][r2] += bb;
    }
    if (op < 2) {
      // per-head normalize: wave's heads = hf*4 + cw*2 + {0,1}
#pragma unroll
      for (int hgl = 0; hgl < 2; hgl++) {
        float sc = 1.0f;
        if (op == 0)
          sc = __expf(fminf(lscale[hf * 4 + cw * 2 + hgl], 4.6051702f)) *
               1.44269504f;
#pragma unroll
        for (int r2 = 0; r2 < 4; r2++) {
          float ss = acc[2 * hgl][r2] * acc[2 * hgl][r2] +
                     acc[2 * hgl + 1][r2] * acc[2 * hgl + 1][r2];
          ss += __shfl_xor(ss, 1, 64);
          ss += __shfl_xor(ss, 2, 64);
          ss += __shfl_xor(ss, 4, 64);
          ss += __shfl_xor(ss, 8, 64);
          float rn = sc / fmaxf(sqrtf(ss), 1e-12f);
          acc[2 * hgl][r2] *= rn;
          acc[2 * hgl + 1][r2] *= rn;
        }
      }
      half_t* tb = (op == 0) ? qbuf : kbuf;
#pragma unroll
      for (int ngl = 0; ngl < 4; ngl++)
#pragma unroll
        for (int r2 = 0; r2 < 4; r2++)
          tb[(rw * 16 + quad * 4 + r2) * 136 + (cw * 4 + ngl) * 16 + l] =
              (half_t)acc[ngl][r2];
    } else {
#pragma unroll
      for (int ngl = 0; ngl < 4; ngl++) {
        int col = (cw * 4 + ngl) * 16 + l;
        half4 hv;
#pragma unroll
        for (int r2 = 0; r2 < 4; r2++) hv[r2] = (half_t)acc[ngl][r2];
        *(half4*)(vbuf + col * 36 + rw * 16 + quad * 4) = hv;
      }
    }
  }
  __syncthreads();  // the ONLY barrier

  // q/k stores: coalesced half8 to [b][h][n][32]
#pragma unroll
  for (int i = 0; i < 2; i++) {
    int idx = t + 256 * i;
    int row = idx >> 4, colc = (idx & 15) * 8;
    int head = hf * 4 + (colc >> 5), d = colc & 31;
    size_t off = (((size_t)b * 8 + head) * 1024 + n0 + row) * 32 + d;
    *(half8*)(qf + off) = *(const half8*)(qbuf + row * 136 + colc);
    *(half8*)(kf + off) = *(const half8*)(kbuf + row * 136 + colc);
  }
  // v stores: coalesced dword to [b][h][d][n]
#pragma unroll
  for (int i = 0; i < 8; i++) {
    int idx = t + 256 * i;
    int col = idx >> 4, rp = idx & 15;
    unsigned int val = *(const unsigned int*)(vbuf + col * 36 + rp * 2);
    int head = hf * 4 + (col >> 5);
    int d = col & 31;
    *(unsigned int*)((char*)vf + (((((size_t)b * 8 + head) * 32 + d) * 1024) +
                                  n0 + rp * 2) * 2) = val;
  }
}

// ---------------------------------------------------------------------------
// attn_mfma: barrier-free flash attention, high occupancy.
// 1-D grid 2048: id = qt*128 + (b*8+h); blocks of one (b,h) congruent mod 8
// -> same XCD.  256 thr (4 waves); wave owns 16 q-rows (one strip).
// P~ = exp2(QK + biastab), scales pre-folded.  One barrier (bias stage).
// ---------------------------------------------------------------------------
__global__ __launch_bounds__(256, 6) void attn_mfma(
    const half_t* __restrict__ qf, const half_t* __restrict__ kf,
    const half_t* __restrict__ vf, const float* __restrict__ tabh2,
    half_t* __restrict__ ao) {
  __shared__ float sb2[33 * 63];      // bias slice: dih-local in [0,33)
  __shared__ half_t pa[4 * 16 * 80];  // per-wave P~ [qrow][key], stride 80

  int id = blockIdx.x;
  int qt = id >> 7;          // 0..15, 64 q-rows per block
  int bh = id & 127;
  int h = bh & 7, b = bh >> 3;
  int t = threadIdx.x;
  int lane = t & 63, wv = t >> 6, l = lane & 15, quad = lane >> 4;
  size_t bhs = (size_t)b * 8 + h;
  const half_t* kbase = kf + bhs * 1024 * 32;
  const half_t* vbase = vf + bhs * 32 * 1024;

  // stage bias slice: global dih in [qt*2, qt*2+33)
  for (int i = t; i < 2079; i += 256)
    sb2[i] = tabh2[h * 3969 + qt * 126 + i];

  int row0 = qt * 64 + wv * 16;
  int iw0 = (wv & 1) * 16;
  int whalf = wv >> 1;

  half8 qfr = *(const half8*)(qf + (bhs * 1024 + row0 + l) * 32 + quad * 8);

  float4v o0 = {0.f, 0.f, 0.f, 0.f}, o1 = {0.f, 0.f, 0.f, 0.f};
  float run_l = 0.0f;
  half_t* paw = pa + wv * 16 * 80;
  __syncthreads();  // the ONLY barrier

#pragma unroll 2
  for (int kt = 0; kt < 16; kt++) {
    half8 kfr[4], v0fr[2], v1fr[2];
#pragma unroll
    for (int nt = 0; nt < 4; nt++)
      kfr[nt] =
          *(const half8*)(kbase + (kt * 64 + nt * 16 + l) * 32 + quad * 8);
#pragma unroll
    for (int ks = 0; ks < 2; ks++) {
      v0fr[ks] =
          *(const half8*)(vbase + l * 1024 + kt * 64 + ks * 32 + quad * 8);
      v1fr[ks] = *(const half8*)(vbase + (16 + l) * 1024 + kt * 64 + ks * 32 +
                                 quad * 8);
    }
    float4v sres[4];
#pragma unroll
    for (int nt = 0; nt < 4; nt++) {
      int base = (whalf - 2 * kt - (nt >> 1) + 31) * 63 + iw0 + l + 31 -
                 (nt & 1) * 16 - quad * 4;
      float4v c;
      c[0] = sb2[base];
      c[1] = sb2[base - 1];
      c[2] = sb2[base - 2];
      c[3] = sb2[base - 3];
      sres[nt] = mfma16(kfr[nt], qfr, c);
    }
#pragma unroll
    for (int nt = 0; nt < 4; nt++) {
      half4 ph;
#pragma unroll
      for (int r2 = 0; r2 < 4; r2++) {
        float p = exp2f(sres[nt][r2]);
        run_l += p;
        ph[r2] = (half_t)p;
      }
      *(half4*)(paw + l * 80 + nt * 16 + quad * 4) = ph;
    }
#pragma unroll
    for (int ks = 0; ks < 2; ks++) {
      half8 pfr = *(const half8*)(paw + l * 80 + ks * 32 + quad * 8);
      o0 = mfma16(pfr, v0fr[ks], o0);
      o1 = mfma16(pfr, v1fr[ks], o1);
    }
  }

  run_l += __shfl_xor(run_l, 16, 64);
  run_l += __shfl_xor(run_l, 32, 64);
  float rli = 1.0f / run_l;

#pragma unroll
  for (int r2 = 0; r2 < 4; r2++) {
    float linv = __shfl(rli, 20 * quad + r2, 64);
    size_t rowaddr =
        ((size_t)b * 1024 + row0 + quad * 4 + r2) * 256 + h * 32;
    ao[rowaddr + l] = (half_t)(o0[r2] * linv);
    ao[rowaddr + 16 + l] = (half_t)(o1[r2] * linv);
  }
}

// ---------------------------------------------------------------------------
// proj_mfma: output projection, fp32 out [b][ch][n] via LDS transpose.
// grid (512 rowtiles-of-32, 2 hf) x 256.  W-frags direct from global.
// ---------------------------------------------------------------------------
__global__ __launch_bounds__(256, 4) void proj_mfma(
    const half_t* __restrict__ ao, const half_t* __restrict__ wfrag,
    const float* __restrict__ bws, float* __restrict__ out) {
  __shared__ float yt[128 * 36];
  int t = threadIdx.x;
  int lane = t & 63, wv = t >> 6, l = lane & 15, quad = lane >> 4;
  int rw = wv & 1, cw = wv >> 1;
  int hf = blockIdx.y;
  int m0 = blockIdx.x * 32;
  int b = m0 >> 10, n0 = m0 & 1023;

  half8 afr[4];
  const half_t* ab =
      ao + ((size_t)m0 + rw * 16 + l) * 256 + hf * 128 + quad * 8;
#pragma unroll
  for (int ks = 0; ks < 4; ks++) afr[ks] = *(const half8*)(ab + ks * 32);

  const half_t* wfb = wfrag + (6 + hf) * 16384;
#pragma unroll
  for (int ngl = 0; ngl < 4; ngl++) {
    int ng = cw * 4 + ngl;
    float4v c = {0.f, 0.f, 0.f, 0.f};
#pragma unroll
    for (int ks = 0; ks < 4; ks++) {
      half8 bfrag = *(const half8*)(wfb + ((ng * 4 + ks) * 64 + lane) * 8);
      c = mfma16(afr[ks], bfrag, c);
    }
    float bb = bws[(6 + hf) * 128 + ng * 16 + l];
#pragma unroll
    for (int r2 = 0; r2 < 4; r2++) c[r2] += bb;
    *(float4v*)(yt + (ng * 16 + l) * 36 + rw * 16 + quad * 4) = c;
  }
  __syncthreads();
#pragma unroll
  for (int i = 0; i < 4; i++) {
    int idx = t + 256 * i;
    int col = idx >> 3, rg = idx & 7;
    float4v vv = *(const float4v*)(yt + col * 36 + rg * 4);
    *(float4v*)(out + ((size_t)b * 256 + hf * 128 + col) * 1024 + n0 +
                rg * 4) = vv;
  }
}

// ---------------------------------------------------------------------------
extern "C" void kernel_launch(void* const* d_in, const int* in_sizes, int n_in,
                              void* d_out, int out_size, void* d_ws,
                              size_t ws_size, hipStream_t stream) {
  (void)in_sizes; (void)n_in; (void)out_size; (void)ws_size;
  const float* x = (const float*)d_in[0];

  half_t* ws = (half_t*)d_ws;
  half_t* qfp = ws;                    // [16][8][1024][32] f16
  half_t* kfp = ws + 4194304;          // [16][8][1024][32] f16
  half_t* vfp = ws + 8388608;          // [16][8][32][1024] f16 (transposed)
  half_t* aop = ws + 12582912;         // [16384][256] f16
  half_t* wfp = ws + 16777216;         // 8 x 16384 f16, fragment layout
  float* tabh2 = (float*)((char*)d_ws + 33816576);  // [8][3969] f32
  float* bws = (float*)((char*)d_ws + 33943584);    // [8][128] f32

  PtrArr8 wsrc, bsrc;
  const int widx[8] = {1, 3, 5, 7, 9, 11, 13, 15};
  for (int i = 0; i < 8; i++) {
    wsrc.p[i] = (const float*)d_in[widx[i]];
    bsrc.p[i] = (const float*)d_in[widx[i] + 1];
  }

  prep_fused<<<144, 256, 0, stream>>>(
      wsrc, bsrc, (const float*)d_in[18], (const float*)d_in[19],
      (const float*)d_in[20], (const float*)d_in[17], wfp, bws, tabh2);
  qkv_mfma<<<dim3(512, 2), 256, 0, stream>>>(x, wfp, (const float*)d_in[17],
                                             bws, qfp, kfp, vfp);
  attn_mfma<<<2048, 256, 0, stream>>>(qfp, kfp, vfp, tabh2, aop);
  proj_mfma<<<dim3(512, 2), 256, 0, stream>>>(aop, wfp, bws, (float*)d_out);
}

// Round 10
// 235.319 us; speedup vs baseline: 1.0434x; 1.0434x over previous
//
#include <hip/hip_runtime.h>
#include <cmath>

// ---------------------------------------------------------------------------
// SwinV2-style window attention, f16-MFMA implementation.  Round 10.
//
// R9->R10:
//  * attn: __launch_bounds__(256,6) -> (256,4).  The 6-waves/EU bound capped
//    VGPRs at ~40 and spilled K/V fragments to scratch (WRITE_SIZE 8->24 MB,
//    dur 66->125 us).  (256,4) = 128-VGPR cap, no spill; grid stays 2048
//    blocks = 8 blocks/CU (LDS-limited), keeping R9's occupancy gain.
//  * pa stride 80 -> 88 halves (176 B): row bank-class 12*l mod 32 -> 2-way
//    (free per m136); 80 was 4-way (1.58x).
// ---------------------------------------------------------------------------

typedef _Float16 half_t;
typedef __attribute__((ext_vector_type(4))) _Float16 half4;
typedef __attribute__((ext_vector_type(8))) _Float16 half8;
typedef __attribute__((ext_vector_type(4))) float float4v;

static __device__ __forceinline__ float4v mfma16(half8 a, half8 b, float4v c) {
  return __builtin_amdgcn_mfma_f32_16x16x32_f16(a, b, c, 0, 0, 0);
}

struct PtrArr8 { const float* p[8]; };

// ---------------------------------------------------------------------------
// prep_fused: blocks 0..127 = prep_w (fp32 W -> f16 (+I), fragment layout);
// blocks 128..143 = bias_mlp table.
// ---------------------------------------------------------------------------
__global__ __launch_bounds__(256) void prep_fused(
    PtrArr8 wsrc, PtrArr8 bsrc, const float* __restrict__ w1,
    const float* __restrict__ b1, const float* __restrict__ w2,
    const float* __restrict__ ls, half_t* __restrict__ wf,
    float* __restrict__ bws, float* __restrict__ tabh2) {
  int t = threadIdx.x;
  if (blockIdx.x < 128) {
    int y = blockIdx.x & 7, xb = blockIdx.x >> 3;
    const float* src = nullptr;
    const float* bs = nullptr;
#pragma unroll
    for (int i = 0; i < 8; i++)
      if (i == y) { src = wsrc.p[i]; bs = bsrc.p[i]; }
    int flat = (xb * 256 + t) * 4;
    float4 w = *(const float4*)(src + flat);
    int j = flat >> 7, k = flat & 127;
    if (y < 6) {
      if (k == j)     w.x += 1.0f;
      if (k + 1 == j) w.y += 1.0f;
      if (k + 2 == j) w.z += 1.0f;
      if (k + 3 == j) w.w += 1.0f;
    }
    half4 h;
    h[0] = (half_t)w.x;
    h[1] = (half_t)w.y;
    h[2] = (half_t)w.z;
    h[3] = (half_t)w.w;
    int ng = j >> 4, l = j & 15, ks = k >> 5, quad = (k >> 3) & 3, o8 = k & 7;
    *(half4*)(wf + y * 16384 + ((ng * 4 + ks) * 64 + quad * 16 + l) * 8 +
              o8) = h;
    if (xb == 0 && t < 128) bws[y * 128 + t] = bs[t];
    return;
  }
  // ---- bias MLP part ----
  __shared__ float sw1[256];
  __shared__ float sb1[128];
  __shared__ float sw2[1024];
  sw1[t] = w1[t];
  if (t < 128) sb1[t] = b1[t];
  for (int i = t; i < 1024; i += 256) sw2[i] = w2[i];
  __syncthreads();
  int p = (blockIdx.x - 128) * 256 + t;
  if (p >= 3969) return;
  int ph = p / 63, pw = p % 63;
  float t0 = (float)(ph - 31) * (3.2f / 31.0f);
  float t1 = (float)(pw - 31) * (3.2f / 31.0f);
  t0 = copysignf(1.0f - __expf(-fabsf(t0)), t0);
  t1 = copysignf(1.0f - __expf(-fabsf(t1)), t1);
  float acc[8];
#pragma unroll
  for (int hh = 0; hh < 8; hh++) acc[hh] = 0.0f;
  for (int j = 0; j < 128; j++) {
    float hj = fmaxf(0.0f, t0 * sw1[2 * j] + t1 * sw1[2 * j + 1] + sb1[j]);
#pragma unroll
    for (int hh = 0; hh < 8; hh++) acc[hh] += hj * sw2[hh * 128 + j];
  }
  const float L2E = 1.44269504f;
#pragma unroll
  for (int hh = 0; hh < 8; hh++) {
    float scale = __expf(fminf(ls[hh], 4.6051702f));
    float c14 = 14.0f - (scale + 16.0f) * L2E;
    float bias = 16.0f / (1.0f + __expf(-acc[hh]));
    tabh2[hh * 3969 + p] = bias * L2E + c14;
  }
}

// ---------------------------------------------------------------------------
// qkv_mfma: 3 fused linears (residual folded into W), per-head q/k norm,
// q scaled by scale*log2e.  grid (512 rowtiles-of-32, 2 hf) x 256.
// W-frags direct from global fragment layout.  ONE barrier epilogue.
// ---------------------------------------------------------------------------
__global__ __launch_bounds__(256, 4) void qkv_mfma(
    const float* __restrict__ x, const half_t* __restrict__ wfrag,
    const float* __restrict__ lscale, const float* __restrict__ bws,
    half_t* __restrict__ qf, half_t* __restrict__ kf,
    half_t* __restrict__ vf) {
  __shared__ half_t qbuf[32 * 136];
  __shared__ half_t kbuf[32 * 136];
  __shared__ half_t vbuf[128 * 36];
  int t = threadIdx.x;
  int lane = t & 63, wv = t >> 6, l = lane & 15, quad = lane >> 4;
  int rw = wv & 1, cw = wv >> 1;
  int hf = blockIdx.y;
  int m0 = blockIdx.x * 32;
  int b = m0 >> 10, n0 = m0 & 1023;

  // A fragments: 16 rows (rw strip), this half's 128 channels.
  half8 afr[4];
  {
    const float* xb =
        x + ((size_t)b * 256 + hf * 128) * 1024 + n0 + rw * 16 + l;
#pragma unroll
    for (int ks = 0; ks < 4; ks++) {
      half8 a;
#pragma unroll
      for (int j = 0; j < 8; j++)
        a[j] = (half_t)xb[(size_t)(ks * 32 + quad * 8 + j) * 1024];
      afr[ks] = a;
    }
  }

#pragma unroll
  for (int op = 0; op < 3; op++) {
    int combo = op * 2 + hf;
    const half_t* wfb = wfrag + combo * 16384;
    float4v acc[4];
#pragma unroll
    for (int ngl = 0; ngl < 4; ngl++) {
      int ng = cw * 4 + ngl;
      float4v c = {0.f, 0.f, 0.f, 0.f};
#pragma unroll
      for (int ks = 0; ks < 4; ks++) {
        half8 bfrag = *(const half8*)(wfb + ((ng * 4 + ks) * 64 + lane) * 8);
        c = mfma16(afr[ks], bfrag, c);
      }
      acc[ngl] = c;
    }
#pragma unroll
    for (int ngl = 0; ngl < 4; ngl++) {
      float bb = bws[combo * 128 + (cw * 4 + ngl) * 16 + l];
#pragma unroll
      for (int r2 = 0; r2 < 4; r2++) acc[ngl][r2] += bb;
    }
    if (op < 2) {
      // per-head normalize: wave's heads = hf*4 + cw*2 + {0,1}
#pragma unroll
      for (int hgl = 0; hgl < 2; hgl++) {
        float sc = 1.0f;
        if (op == 0)
          sc = __expf(fminf(lscale[hf * 4 + cw * 2 + hgl], 4.6051702f)) *
               1.44269504f;
#pragma unroll
        for (int r2 = 0; r2 < 4; r2++) {
          float ss = acc[2 * hgl][r2] * acc[2 * hgl][r2] +
                     acc[2 * hgl + 1][r2] * acc[2 * hgl + 1][r2];
          ss += __shfl_xor(ss, 1, 64);
          ss += __shfl_xor(ss, 2, 64);
          ss += __shfl_xor(ss, 4, 64);
          ss += __shfl_xor(ss, 8, 64);
          float rn = sc / fmaxf(sqrtf(ss), 1e-12f);
          acc[2 * hgl][r2] *= rn;
          acc[2 * hgl + 1][r2] *= rn;
        }
      }
      half_t* tb = (op == 0) ? qbuf : kbuf;
#pragma unroll
      for (int ngl = 0; ngl < 4; ngl++)
#pragma unroll
        for (int r2 = 0; r2 < 4; r2++)
          tb[(rw * 16 + quad * 4 + r2) * 136 + (cw * 4 + ngl) * 16 + l] =
              (half_t)acc[ngl][r2];
    } else {
#pragma unroll
      for (int ngl = 0; ngl < 4; ngl++) {
        int col = (cw * 4 + ngl) * 16 + l;
        half4 hv;
#pragma unroll
        for (int r2 = 0; r2 < 4; r2++) hv[r2] = (half_t)acc[ngl][r2];
        *(half4*)(vbuf + col * 36 + rw * 16 + quad * 4) = hv;
      }
    }
  }
  __syncthreads();  // the ONLY barrier

  // q/k stores: coalesced half8 to [b][h][n][32]
#pragma unroll
  for (int i = 0; i < 2; i++) {
    int idx = t + 256 * i;
    int row = idx >> 4, colc = (idx & 15) * 8;
    int head = hf * 4 + (colc >> 5), d = colc & 31;
    size_t off = (((size_t)b * 8 + head) * 1024 + n0 + row) * 32 + d;
    *(half8*)(qf + off) = *(const half8*)(qbuf + row * 136 + colc);
    *(half8*)(kf + off) = *(const half8*)(kbuf + row * 136 + colc);
  }
  // v stores: coalesced dword to [b][h][d][n]
#pragma unroll
  for (int i = 0; i < 8; i++) {
    int idx = t + 256 * i;
    int col = idx >> 4, rp = idx & 15;
    unsigned int val = *(const unsigned int*)(vbuf + col * 36 + rp * 2);
    int head = hf * 4 + (col >> 5);
    int d = col & 31;
    *(unsigned int*)((char*)vf + (((((size_t)b * 8 + head) * 32 + d) * 1024) +
                                  n0 + rp * 2) * 2) = val;
  }
}

// ---------------------------------------------------------------------------
// attn_mfma: barrier-free flash attention, high occupancy, no spills.
// 1-D grid 2048: id = qt*128 + (b*8+h); blocks of one (b,h) congruent mod 8
// -> same XCD.  256 thr (4 waves); wave owns 16 q-rows (one strip).
// P~ = exp2(QK + biastab), scales pre-folded.  One barrier (bias stage).
// ---------------------------------------------------------------------------
__global__ __launch_bounds__(256, 4) void attn_mfma(
    const half_t* __restrict__ qf, const half_t* __restrict__ kf,
    const half_t* __restrict__ vf, const float* __restrict__ tabh2,
    half_t* __restrict__ ao) {
  __shared__ float sb2[33 * 63];      // bias slice: dih-local in [0,33)
  __shared__ half_t pa[4 * 16 * 88];  // per-wave P~ [qrow][key], stride 88

  int id = blockIdx.x;
  int qt = id >> 7;          // 0..15, 64 q-rows per block
  int bh = id & 127;
  int h = bh & 7, b = bh >> 3;
  int t = threadIdx.x;
  int lane = t & 63, wv = t >> 6, l = lane & 15, quad = lane >> 4;
  size_t bhs = (size_t)b * 8 + h;
  const half_t* kbase = kf + bhs * 1024 * 32;
  const half_t* vbase = vf + bhs * 32 * 1024;

  // stage bias slice: global dih in [qt*2, qt*2+33)
  for (int i = t; i < 2079; i += 256)
    sb2[i] = tabh2[h * 3969 + qt * 126 + i];

  int row0 = qt * 64 + wv * 16;
  int iw0 = (wv & 1) * 16;
  int whalf = wv >> 1;

  half8 qfr = *(const half8*)(qf + (bhs * 1024 + row0 + l) * 32 + quad * 8);

  float4v o0 = {0.f, 0.f, 0.f, 0.f}, o1 = {0.f, 0.f, 0.f, 0.f};
  float run_l = 0.0f;
  half_t* paw = pa + wv * 16 * 88;
  __syncthreads();  // the ONLY barrier

#pragma unroll 2
  for (int kt = 0; kt < 16; kt++) {
    half8 kfr[4], v0fr[2], v1fr[2];
#pragma unroll
    for (int nt = 0; nt < 4; nt++)
      kfr[nt] =
          *(const half8*)(kbase + (kt * 64 + nt * 16 + l) * 32 + quad * 8);
#pragma unroll
    for (int ks = 0; ks < 2; ks++) {
      v0fr[ks] =
          *(const half8*)(vbase + l * 1024 + kt * 64 + ks * 32 + quad * 8);
      v1fr[ks] = *(const half8*)(vbase + (16 + l) * 1024 + kt * 64 + ks * 32 +
                                 quad * 8);
    }
    float4v sres[4];
#pragma unroll
    for (int nt = 0; nt < 4; nt++) {
      int base = (whalf - 2 * kt - (nt >> 1) + 31) * 63 + iw0 + l + 31 -
                 (nt & 1) * 16 - quad * 4;
      float4v c;
      c[0] = sb2[base];
      c[1] = sb2[base - 1];
      c[2] = sb2[base - 2];
      c[3] = sb2[base - 3];
      sres[nt] = mfma16(kfr[nt], qfr, c);
    }
#pragma unroll
    for (int nt = 0; nt < 4; nt++) {
      half4 ph;
#pragma unroll
      for (int r2 = 0; r2 < 4; r2++) {
        float p = exp2f(sres[nt][r2]);
        run_l += p;
        ph[r2] = (half_t)p;
      }
      *(half4*)(paw + l * 88 + nt * 16 + quad * 4) = ph;
    }
#pragma unroll
    for (int ks = 0; ks < 2; ks++) {
      half8 pfr = *(const half8*)(paw + l * 88 + ks * 32 + quad * 8);
      o0 = mfma16(pfr, v0fr[ks], o0);
      o1 = mfma16(pfr, v1fr[ks], o1);
    }
  }

  run_l += __shfl_xor(run_l, 16, 64);
  run_l += __shfl_xor(run_l, 32, 64);
  float rli = 1.0f / run_l;

#pragma unroll
  for (int r2 = 0; r2 < 4; r2++) {
    float linv = __shfl(rli, 20 * quad + r2, 64);
    size_t rowaddr =
        ((size_t)b * 1024 + row0 + quad * 4 + r2) * 256 + h * 32;
    ao[rowaddr + l] = (half_t)(o0[r2] * linv);
    ao[rowaddr + 16 + l] = (half_t)(o1[r2] * linv);
  }
}

// ---------------------------------------------------------------------------
// proj_mfma: output projection, fp32 out [b][ch][n] via LDS transpose.
// grid (512 rowtiles-of-32, 2 hf) x 256.  W-frags direct from global.
// ---------------------------------------------------------------------------
__global__ __launch_bounds__(256, 4) void proj_mfma(
    const half_t* __restrict__ ao, const half_t* __restrict__ wfrag,
    const float* __restrict__ bws, float* __restrict__ out) {
  __shared__ float yt[128 * 36];
  int t = threadIdx.x;
  int lane = t & 63, wv = t >> 6, l = lane & 15, quad = lane >> 4;
  int rw = wv & 1, cw = wv >> 1;
  int hf = blockIdx.y;
  int m0 = blockIdx.x * 32;
  int b = m0 >> 10, n0 = m0 & 1023;

  half8 afr[4];
  const half_t* ab =
      ao + ((size_t)m0 + rw * 16 + l) * 256 + hf * 128 + quad * 8;
#pragma unroll
  for (int ks = 0; ks < 4; ks++) afr[ks] = *(const half8*)(ab + ks * 32);

  const half_t* wfb = wfrag + (6 + hf) * 16384;
#pragma unroll
  for (int ngl = 0; ngl < 4; ngl++) {
    int ng = cw * 4 + ngl;
    float4v c = {0.f, 0.f, 0.f, 0.f};
#pragma unroll
    for (int ks = 0; ks < 4; ks++) {
      half8 bfrag = *(const half8*)(wfb + ((ng * 4 + ks) * 64 + lane) * 8);
      c = mfma16(afr[ks], bfrag, c);
    }
    float bb = bws[(6 + hf) * 128 + ng * 16 + l];
#pragma unroll
    for (int r2 = 0; r2 < 4; r2++) c[r2] += bb;
    *(float4v*)(yt + (ng * 16 + l) * 36 + rw * 16 + quad * 4) = c;
  }
  __syncthreads();
#pragma unroll
  for (int i = 0; i < 4; i++) {
    int idx = t + 256 * i;
    int col = idx >> 3, rg = idx & 7;
    float4v vv = *(const float4v*)(yt + col * 36 + rg * 4);
    *(float4v*)(out + ((size_t)b * 256 + hf * 128 + col) * 1024 + n0 +
                rg * 4) = vv;
  }
}

// ---------------------------------------------------------------------------
extern "C" void kernel_launch(void* const* d_in, const int* in_sizes, int n_in,
                              void* d_out, int out_size, void* d_ws,
                              size_t ws_size, hipStream_t stream) {
  (void)in_sizes; (void)n_in; (void)out_size; (void)ws_size;
  const float* x = (const float*)d_in[0];

  half_t* ws = (half_t*)d_ws;
  half_t* qfp = ws;                    // [16][8][1024][32] f16
  half_t* kfp = ws + 4194304;          // [16][8][1024][32] f16
  half_t* vfp = ws + 8388608;          // [16][8][32][1024] f16 (transposed)
  half_t* aop = ws + 12582912;         // [16384][256] f16
  half_t* wfp = ws + 16777216;         // 8 x 16384 f16, fragment layout
  float* tabh2 = (float*)((char*)d_ws + 33816576);  // [8][3969] f32
  float* bws = (float*)((char*)d_ws + 33943584);    // [8][128] f32

  PtrArr8 wsrc, bsrc;
  const int widx[8] = {1, 3, 5, 7, 9, 11, 13, 15};
  for (int i = 0; i < 8; i++) {
    wsrc.p[i] = (const float*)d_in[widx[i]];
    bsrc.p[i] = (const float*)d_in[widx[i] + 1];
  }

  prep_fused<<<144, 256, 0, stream>>>(
      wsrc, bsrc, (const float*)d_in[18], (const float*)d_in[19],
      (const float*)d_in[20], (const float*)d_in[17], wfp, bws, tabh2);
  qkv_mfma<<<dim3(512, 2), 256, 0, stream>>>(x, wfp, (const float*)d_in[17],
                                             bws, qfp, kfp, vfp);
  attn_mfma<<<2048, 256, 0, stream>>>(qfp, kfp, vfp, tabh2, aop);
  proj_mfma<<<dim3(512, 2), 256, 0, stream>>>(aop, wfp, bws, (float*)d_out);
}